// Round 3
// baseline (531.839 us; speedup 1.0000x reference)
//
#include <hip/hip_runtime.h>
#include <math.h>

#define NCLS  100
#define ITERS 100

typedef float v2f __attribute__((ext_vector_type(2)));

#if __has_builtin(__builtin_amdgcn_rcpf)
__device__ __forceinline__ float fast_rcp(float x) { return __builtin_amdgcn_rcpf(x); }
#else
__device__ __forceinline__ float fast_rcp(float x) { return 1.0f / x; }
#endif

#if __has_builtin(__builtin_amdgcn_exp2f)
__device__ __forceinline__ float fast_exp2(float x) { return __builtin_amdgcn_exp2f(x); }
#else
__device__ __forceinline__ float fast_exp2(float x) { return exp2f(x); }
#endif

__device__ __forceinline__ float rlane(float v, int l) {
    return __int_as_float(__builtin_amdgcn_readlane(__float_as_int(v), l));
}
__device__ __forceinline__ v2f pk_fma(v2f a, v2f b, v2f c) {
    return __builtin_elementwise_fma(a, b, c);
}

__device__ __forceinline__ float wave_sum(float v) {
#pragma unroll
    for (int m = 32; m > 0; m >>= 1) v += __shfl_xor(v, m, 64);
    return v;
}
__device__ __forceinline__ float wave_max(float v) {
#pragma unroll
    for (int m = 32; m > 0; m >>= 1) v = fmaxf(v, __shfl_xor(v, m, 64));
    return v;
}

// (K x)_{i0,i1}; x distributed: lane p holds x[2p] (s0), x[2p+1] (s1).
// kpE[m] = {w(i1-2m),   w(i1-2m-1)}  -> K[i1][2m], K[i1][2m+1]
// kpO[m] = {w(i1-2m-1), w(i1-2m-2)}  -> K[i0][2m], K[i0][2m+1]
// Duplicated aligned pairs so each v_pk_fma_f32 consumes one whole pair and
// the single broadcast pair bb = {x[2m], x[2m+1]} feeds both rows.
#define MATVEC(dst0, dst1, s0, s1)                                  \
    {                                                               \
        v2f A1 = {0.f, 0.f}, B1 = {0.f, 0.f};                       \
        v2f A0 = {0.f, 0.f}, B0 = {0.f, 0.f};                       \
        _Pragma("unroll")                                           \
        for (int m = 0; m < 50; m += 2) {                           \
            v2f bb0 = { rlane(s0, m), rlane(s1, m) };               \
            A1 = pk_fma(kpE[m], bb0, A1);                           \
            A0 = pk_fma(kpO[m], bb0, A0);                           \
            v2f bb1 = { rlane(s0, m + 1), rlane(s1, m + 1) };       \
            B1 = pk_fma(kpE[m + 1], bb1, B1);                       \
            B0 = pk_fma(kpO[m + 1], bb1, B0);                       \
        }                                                           \
        v2f S1 = A1 + B1;                                           \
        v2f S0 = A0 + B0;                                           \
        dst1 = S1.x + S1.y;                                         \
        dst0 = S0.x + S0.y;                                         \
    }

// scalar accessors (constant j): K[i1][j] and K[i0][j]
#define KE_(j) (((j) & 1) ? kpE[(j) >> 1].y : kpE[(j) >> 1].x)
#define KO_(j) (((j) & 1) ? kpO[(j) >> 1].y : kpO[(j) >> 1].x)

extern "C" __global__ void sk_zero_out(float* out) { out[0] = 0.0f; }

extern "C" __global__ void __launch_bounds__(64)
sk_sinkhorn(const float* __restrict__ pred, const int* __restrict__ target,
            float* __restrict__ out, int rows)
{
    const int r  = blockIdx.x;
    const int l  = threadIdx.x;
    const int i0 = 2 * l;
    const int i1 = i0 + 1;
    const bool active = (i0 < NCLS);

    // ---- marginals: mu = normalize(softmax(pred_row) + STAB) ----
    const float* prow = pred + (size_t)r * NCLS;
    float p0 = active ? prow[i0] : -3.4e38f;
    float p1 = active ? prow[i1] : -3.4e38f;
    float mx = wave_max(fmaxf(p0, p1));
    float e0 = active ? expf(p0 - mx) : 0.0f;
    float e1 = active ? expf(p1 - mx) : 0.0f;
    float S    = wave_sum(e0 + e1);
    float invS = 1.0f / S;
    float mur0 = active ? (e0 * invS + 1e-6f) : 0.0f;
    float mur1 = active ? (e1 * invS + 1e-6f) : 0.0f;
    float Smu  = wave_sum(mur0 + mur1);
    float invM = 1.0f / Smu;
    float mu0 = mur0 * invM, mu1 = mur1 * invM;

    // ---- nu = normalize(one_hot(target) + STAB) ----
    int   tgt = target[r];
    float nr0 = active ? (((i0 == tgt) ? 1.0f : 0.0f) + 1e-6f) : 0.0f;
    float nr1 = active ? (((i1 == tgt) ? 1.0f : 0.0f) + 1e-6f) : 0.0f;
    float Snu  = wave_sum(nr0 + nr1);
    float invN = 1.0f / Snu;
    float nu0 = nr0 * invN, nu1 = nr1 * invN;

    // ---- Toeplitz K-row windows as aligned v2f pairs (exp2 form) ----
    // w(d) = exp(-10 d^2/9801) = exp2(c2 * d^2)
    const float c2 = -10.0f * 1.4426950408889634f / 9801.0f;
    v2f kpE[50], kpO[50];
#pragma unroll
    for (int m = 0; m < 50; ++m) {
        int   d0 = i1 - 2 * m;
        int   d1 = d0 - 1;
        int   d2 = d0 - 2;
        float w0 = fast_exp2(c2 * (float)(d0 * d0));
        float w1 = fast_exp2(c2 * (float)(d1 * d1));
        float w2 = fast_exp2(c2 * (float)(d2 * d2));
        kpE[m] = (v2f){w0, w1};
        kpO[m] = (v2f){w1, w2};
    }

    // ---- Sinkhorn scaling, exp domain: a = mu/(K b), b = nu/(K a) ----
    float a0 = 0.f, a1 = 0.f, b0 = 1.0f, b1 = 1.0f;
#pragma unroll 1
    for (int it = 0; it < ITERS; ++it) {
        float t0, t1;
        MATVEC(t0, t1, b0, b1);
        a0 = mu0 * fast_rcp(t0);
        a1 = mu1 * fast_rcp(t1);
        float s0, s1;
        MATVEC(s0, s1, a0, a1);
        b0 = nu0 * fast_rcp(s0);
        b1 = nu1 * fast_rcp(s1);
    }

    // ---- epilogue: P = a K b + STAB, renorm rows to mu, cols to nu ----
    float t0, t1;
    MATVEC(t0, t1, b0, b1);
    float row0 = fmaf(a0, t0, (float)NCLS * 1e-6f);
    float row1 = fmaf(a1, t1, (float)NCLS * 1e-6f);
    float scl0 = mu0 * fast_rcp(row0);   // inactive lanes: mu=0 -> 0
    float scl1 = mu1 * fast_rcp(row1);
    float ap0 = a0 * scl0, ap1 = a1 * scl1;
    float Ssum = wave_sum(scl0 + scl1);

    // q_j=(K a')_j, mm_j=((K.C) a')_j, cs_j=(C scl)_j at j = i0, i1
    float q0 = 0.f, q1 = 0.f, mm0 = 0.f, mm1 = 0.f, cs0 = 0.f, cs1 = 0.f;
    const float fi0 = (float)i0;
    const float inv = 1.0f / 9801.0f;
#pragma unroll
    for (int j = 0; j < NCLS; j += 2) {
        float alo = rlane(ap0,  j >> 1);
        float ahi = rlane(ap1,  j >> 1);
        float slo = rlane(scl0, j >> 1);
        float shi = rlane(scl1, j >> 1);
        float d0 = fi0 - (float)j;
        float em  = (d0 - 1.0f) * (d0 - 1.0f) * inv;  // C(i0, j+1)
        float e0c = d0 * d0 * inv;                    // C(i0,j) = C(i1,j+1)
        float ep  = (d0 + 1.0f) * (d0 + 1.0f) * inv;  // C(i1, j)
        float klo0 = KO_(j), khi0 = KO_(j + 1);       // K[i0][j], K[i0][j+1]
        float klo1 = KE_(j), khi1 = KE_(j + 1);       // K[i1][j], K[i1][j+1]
        q0  = fmaf(klo0, alo, q0);        q0  = fmaf(khi0, ahi, q0);
        q1  = fmaf(klo1, alo, q1);        q1  = fmaf(khi1, ahi, q1);
        mm0 = fmaf(klo0 * e0c, alo, mm0); mm0 = fmaf(khi0 * em,  ahi, mm0);
        mm1 = fmaf(klo1 * ep,  alo, mm1); mm1 = fmaf(khi1 * e0c, ahi, mm1);
        cs0 = fmaf(e0c, slo, cs0);        cs0 = fmaf(em,  shi, cs0);
        cs1 = fmaf(ep,  slo, cs1);        cs1 = fmaf(e0c, shi, cs1);
    }

    // colsum_j = b_j*q_j + STAB*sum(scl); cost = sum_j nu_j/colsum_j*(b_j*mm_j + STAB*cs_j)
    float z = 0.0f;
    if (active) {
        float col0 = fmaf(b0, q0, 1e-6f * Ssum);
        float col1 = fmaf(b1, q1, 1e-6f * Ssum);
        float in0  = fmaf(b0, mm0, 1e-6f * cs0);
        float in1  = fmaf(b1, mm1, 1e-6f * cs1);
        z = nu0 * fast_rcp(col0) * in0 + nu1 * fast_rcp(col1) * in1;
    }
    float rc = wave_sum(z);
    if (l == 0) atomicAdd(out, rc / (float)rows);
}

extern "C" void kernel_launch(void* const* d_in, const int* in_sizes, int n_in,
                              void* d_out, int out_size, void* d_ws, size_t ws_size,
                              hipStream_t stream)
{
    const float* pred   = (const float*)d_in[0];
    const int*   target = (const int*)d_in[1];
    float*       out    = (float*)d_out;
    const int    rows   = in_sizes[0] / NCLS;   // 4096

    hipLaunchKernelGGL(sk_zero_out, dim3(1), dim3(1), 0, stream, out);
    hipLaunchKernelGGL(sk_sinkhorn, dim3(rows), dim3(64), 0, stream,
                       pred, target, out, rows);
}

// Round 5
// 423.133 us; speedup vs baseline: 1.2569x; 1.2569x over previous
//
#include <hip/hip_runtime.h>
#include <math.h>

#define NCLS  100
#define ITERS 100

typedef _Float16 h2 __attribute__((ext_vector_type(2)));

#if __has_builtin(__builtin_amdgcn_rcpf)
__device__ __forceinline__ float fast_rcp(float x) { return __builtin_amdgcn_rcpf(x); }
#else
__device__ __forceinline__ float fast_rcp(float x) { return 1.0f / x; }
#endif

#if __has_builtin(__builtin_amdgcn_exp2f)
__device__ __forceinline__ float fast_exp2(float x) { return __builtin_amdgcn_exp2f(x); }
#else
__device__ __forceinline__ float fast_exp2(float x) { return exp2f(x); }
#endif

__device__ __forceinline__ float rlane(float v, int l) {
    return __int_as_float(__builtin_amdgcn_readlane(__float_as_int(v), l));
}
// broadcast a packed half2 (one 32-bit reg) from lane l -> wave-uniform (SGPR)
__device__ __forceinline__ h2 rlane_h2(h2 v, int l) {
    int i = __builtin_bit_cast(int, v);
    i = __builtin_amdgcn_readlane(i, l);
    return __builtin_bit_cast(h2, i);
}
// pack two f32 -> f16x2 (v_cvt_pkrtz_f16_f32); bit_cast fixes the
// __fp16-vector vs _Float16-vector type mismatch (same 32-bit pattern).
__device__ __forceinline__ h2 pack_h2(float x, float y) {
    return __builtin_bit_cast(h2, __builtin_amdgcn_cvt_pkrtz(x, y));
}

#if __has_builtin(__builtin_amdgcn_fdot2)
__device__ __forceinline__ float fdot2(h2 a, h2 b, float c) {
    return __builtin_amdgcn_fdot2(a, b, c, false);   // v_dot2_f32_f16
}
#else
__device__ __forceinline__ float fdot2(h2 a, h2 b, float c) {
    c = fmaf((float)a.x, (float)b.x, c);             // v_fma_mix fallback
    c = fmaf((float)a.y, (float)b.y, c);
    return c;
}
#endif

__device__ __forceinline__ float wave_sum(float v) {
#pragma unroll
    for (int m = 32; m > 0; m >>= 1) v += __shfl_xor(v, m, 64);
    return v;
}
__device__ __forceinline__ float wave_max(float v) {
#pragma unroll
    for (int m = 32; m > 0; m >>= 1) v = fmaxf(v, __shfl_xor(v, m, 64));
    return v;
}

// (K x)_{i0,i1}; x distributed: lane p holds x[2p] (s0), x[2p+1] (s1), all > 0.
// K rows in f16 column-pairs: kh0[m]={K[i0][2m],K[i0][2m+1]}, kh1 likewise.
// Range-compress x by its wave max into f16 (exact rescale, multiplied back);
// one readlane broadcasts a packed x-pair; dot2 accumulates in f32.
#define MATVEC(dst0, dst1, s0, s1)                                  \
    {                                                               \
        float mxv = wave_max(fmaxf(s0, s1));                        \
        float inv = fast_rcp(mxv);                                  \
        h2 xp = pack_h2(s0 * inv, s1 * inv);                        \
        float A0 = 0.f, B0 = 0.f, A1 = 0.f, B1 = 0.f;               \
        _Pragma("unroll")                                           \
        for (int m = 0; m < 50; m += 2) {                           \
            h2 x0 = rlane_h2(xp, m);                                \
            A0 = fdot2(kh0[m], x0, A0);                             \
            A1 = fdot2(kh1[m], x0, A1);                             \
            h2 x1 = rlane_h2(xp, m + 1);                            \
            B0 = fdot2(kh0[m + 1], x1, B0);                         \
            B1 = fdot2(kh1[m + 1], x1, B1);                         \
        }                                                           \
        dst0 = (A0 + B0) * mxv;                                     \
        dst1 = (A1 + B1) * mxv;                                     \
    }

extern "C" __global__ void sk_zero_out(float* out) { out[0] = 0.0f; }

extern "C" __global__ void __launch_bounds__(64, 4)
sk_sinkhorn(const float* __restrict__ pred, const int* __restrict__ target,
            float* __restrict__ out, int rows)
{
    const int r  = blockIdx.x;
    const int l  = threadIdx.x;
    const int i0 = 2 * l;
    const int i1 = i0 + 1;
    const bool active = (i0 < NCLS);

    // ---- marginals: mu = normalize(softmax(pred_row) + STAB) ----
    const float* prow = pred + (size_t)r * NCLS;
    float p0 = active ? prow[i0] : -3.4e38f;
    float p1 = active ? prow[i1] : -3.4e38f;
    float mx = wave_max(fmaxf(p0, p1));
    float e0 = active ? expf(p0 - mx) : 0.0f;
    float e1 = active ? expf(p1 - mx) : 0.0f;
    float S    = wave_sum(e0 + e1);
    float invS = 1.0f / S;
    float mur0 = active ? (e0 * invS + 1e-6f) : 0.0f;
    float mur1 = active ? (e1 * invS + 1e-6f) : 0.0f;
    float Smu  = wave_sum(mur0 + mur1);
    float invM = 1.0f / Smu;
    float mu0 = mur0 * invM, mu1 = mur1 * invM;

    // ---- nu = normalize(one_hot(target) + STAB) ----
    int   tgt = target[r];
    float nr0 = active ? (((i0 == tgt) ? 1.0f : 0.0f) + 1e-6f) : 0.0f;
    float nr1 = active ? (((i1 == tgt) ? 1.0f : 0.0f) + 1e-6f) : 0.0f;
    float Snu  = wave_sum(nr0 + nr1);
    float invN = 1.0f / Snu;
    float nu0 = nr0 * invN, nu1 = nr1 * invN;

    // ---- Toeplitz K rows, f16 column-pairs: w(d) = exp2(c2*d^2) ----
    // C_ij = (i-j)^2/9801, K = exp(-10*C); c2 = -10*log2(e)/9801
    const float c2 = -14.4269504089f / 9801.0f;
    h2 kh0[50], kh1[50];
#pragma unroll
    for (int m = 0; m < 50; ++m) {
        int   e  = i1 - 2 * m;
        float w0 = fast_exp2(c2 * (float)(e * e));             // w(i1-2m)
        float w1 = fast_exp2(c2 * (float)((e - 1) * (e - 1))); // w(i1-2m-1)=w(i0-2m)
        float w2 = fast_exp2(c2 * (float)((e - 2) * (e - 2))); // w(i0-2m-1)
        kh1[m] = pack_h2(w0, w1);
        kh0[m] = pack_h2(w1, w2);
    }

    // ---- Sinkhorn scaling, exp domain: a = mu/(K b), b = nu/(K a) ----
    float a0 = 0.f, a1 = 0.f, b0 = 1.0f, b1 = 1.0f;
#pragma unroll 1
    for (int it = 0; it < ITERS; ++it) {
        float t0, t1;
        MATVEC(t0, t1, b0, b1);
        a0 = mu0 * fast_rcp(t0);
        a1 = mu1 * fast_rcp(t1);
        float s0, s1;
        MATVEC(s0, s1, a0, a1);
        b0 = nu0 * fast_rcp(s0);
        b1 = nu1 * fast_rcp(s1);
    }

    // ---- epilogue (fp32): P = aKb + STAB, renorm rows to mu, cols to nu ----
    float t0, t1;
    MATVEC(t0, t1, b0, b1);
    float row0 = fmaf(a0, t0, (float)NCLS * 1e-6f);
    float row1 = fmaf(a1, t1, (float)NCLS * 1e-6f);
    float scl0 = mu0 * fast_rcp(row0);   // inactive lanes: mu=0 -> 0
    float scl1 = mu1 * fast_rcp(row1);
    float ap0 = a0 * scl0, ap1 = a1 * scl1;
    float Ssum = wave_sum(scl0 + scl1);

    // q_j=(K a')_j, mm_j=((K.C) a')_j, cs_j=(C scl)_j at j = i0, i1
    // K recomputed in fp32 from C via exp2 (runs once; kh regs dead here).
    float q0 = 0.f, q1 = 0.f, mm0 = 0.f, mm1 = 0.f, cs0 = 0.f, cs1 = 0.f;
    const float fi0 = (float)i0;
    const float inv = 1.0f / 9801.0f;
    const float c3  = -14.4269504089f;   // K = exp2(c3 * C)
#pragma unroll
    for (int j = 0; j < NCLS; j += 2) {
        float alo = rlane(ap0,  j >> 1);
        float ahi = rlane(ap1,  j >> 1);
        float slo = rlane(scl0, j >> 1);
        float shi = rlane(scl1, j >> 1);
        float d0  = fi0 - (float)j;
        float em  = (d0 - 1.0f) * (d0 - 1.0f) * inv;  // C(i0, j+1)
        float e0c = d0 * d0 * inv;                    // C(i0,j) = C(i1,j+1)
        float ep  = (d0 + 1.0f) * (d0 + 1.0f) * inv;  // C(i1, j)
        float klo0 = fast_exp2(c3 * e0c);             // K[i0][j]
        float khi0 = fast_exp2(c3 * em);              // K[i0][j+1]
        float klo1 = fast_exp2(c3 * ep);              // K[i1][j]
        float khi1 = klo0;                            // K[i1][j+1]
        q0  = fmaf(klo0, alo, q0);        q0  = fmaf(khi0, ahi, q0);
        q1  = fmaf(klo1, alo, q1);        q1  = fmaf(khi1, ahi, q1);
        mm0 = fmaf(klo0 * e0c, alo, mm0); mm0 = fmaf(khi0 * em,  ahi, mm0);
        mm1 = fmaf(klo1 * ep,  alo, mm1); mm1 = fmaf(khi1 * e0c, ahi, mm1);
        cs0 = fmaf(e0c, slo, cs0);        cs0 = fmaf(em,  shi, cs0);
        cs1 = fmaf(ep,  slo, cs1);        cs1 = fmaf(e0c, shi, cs1);
    }

    // colsum_j = b_j*q_j + STAB*sum(scl); cost = sum_j nu_j/colsum_j*(b_j*mm_j + STAB*cs_j)
    float z = 0.0f;
    if (active) {
        float col0 = fmaf(b0, q0, 1e-6f * Ssum);
        float col1 = fmaf(b1, q1, 1e-6f * Ssum);
        float in0  = fmaf(b0, mm0, 1e-6f * cs0);
        float in1  = fmaf(b1, mm1, 1e-6f * cs1);
        z = nu0 * fast_rcp(col0) * in0 + nu1 * fast_rcp(col1) * in1;
    }
    float rc = wave_sum(z);
    if (l == 0) atomicAdd(out, rc / (float)rows);
}

extern "C" void kernel_launch(void* const* d_in, const int* in_sizes, int n_in,
                              void* d_out, int out_size, void* d_ws, size_t ws_size,
                              hipStream_t stream)
{
    const float* pred   = (const float*)d_in[0];
    const int*   target = (const int*)d_in[1];
    float*       out    = (float*)d_out;
    const int    rows   = in_sizes[0] / NCLS;   // 4096

    hipLaunchKernelGGL(sk_zero_out, dim3(1), dim3(1), 0, stream, out);
    hipLaunchKernelGGL(sk_sinkhorn, dim3(rows), dim3(64), 0, stream,
                       pred, target, out, rows);
}